// Round 1
// baseline (1186.897 us; speedup 1.0000x reference)
//
#include <hip/hip_runtime.h>

namespace {
constexpr int B_ = 8, H_ = 16, CI_ = 16, O_ = 16, P_ = 14;
constexpr int P2_ = P_ * P_;            // 196
constexpr int K2CI_ = 9 * CI_;          // 144
constexpr int NV_ = K2CI_ * O_;         // 2304  (z elements per (b,p2) block)
constexpr float EPS_ = 1e-9f;
constexpr float LOG2PI_ = 1.8378770664093453f;

__device__ __forceinline__ float cnt1(int h) {
  // number of kernel offsets ki in [0,3) with 0 <= h-ki <= P_-1
  int lo = (h - (P_ - 1)) > 0 ? (h - (P_ - 1)) : 0;
  int hi = h < 2 ? h : 2;
  return (float)(hi - lo + 1);
}

// MODE 0: rr uniform, write z.  MODE 1: rr from softmax, write z.  MODE 2: rr from softmax, write outputs.
template <int MODE>
__global__ __launch_bounds__(256) void caps_main(
    const float* __restrict__ pose, const float* __restrict__ act,
    const float* __restrict__ w, const float* __restrict__ beta_a,
    const float* __restrict__ beta_v, const float* __restrict__ zin,
    const float* __restrict__ gmax, const float* __restrict__ gden,
    float* __restrict__ zout, float* __restrict__ out) {
  __shared__ float pose_s[K2CI_ * 16];  // [k2ci][16] pose matrices
  __shared__ float act_s[K2CI_];
  __shared__ float rr_s[NV_];           // rr'[k][o] = rr*act ; reused as z staging

  const int bid = blockIdx.x;
  const int b = bid / P2_;
  const int p2 = bid % P2_;
  const int pi = p2 / P_;
  const int pj = p2 % P_;
  const int tid = threadIdx.x;

  // ---- stage pose patch (3 contiguous 768-float rows) and activations ----
  for (int ki = 0; ki < 3; ++ki) {
    const float* src = pose + (size_t)((b * H_ + pi + ki) * H_ + pj) * CI_ * 16;
    for (int j = tid; j < 3 * CI_ * 16; j += 256) pose_s[ki * 768 + j] = src[j];
    const float* asrc = act + (size_t)((b * H_ + pi + ki) * H_ + pj) * CI_;
    if (tid < 3 * CI_) act_s[ki * 48 + tid] = asrc[tid];
  }
  __syncthreads();

  // ---- stage rr'[k][o] = rr[k][o] * act_i[k] ----
  for (int idx = tid; idx < NV_; idx += 256) {
    const int k = idx >> 4;
    const int kk = k >> 4, ci = k & 15;
    const int ki = kk / 3, kj = kk - 3 * ki;
    const int h = pi + ki, w2 = pj + kj;
    float val;
    if (MODE == 0) {
      val = act_s[k] / (16.0f * cnt1(h) * cnt1(w2));
    } else {
      const float zv = zin[(size_t)bid * NV_ + idx];
      const int cidx = ((b * H_ + h) * H_ + w2) * CI_ + (k & 15);
      const float rr = __expf(zv - gmax[cidx]) / (gden[cidx] + EPS_);
      val = rr * act_s[k];
      (void)ci;
    }
    rr_s[idx] = val;
  }
  __syncthreads();

  // ---- per-wave: 4 output capsules each; lane = kg*16 + d ----
  const int lane = tid & 63;
  const int wv = tid >> 6;
  const int d = lane & 15;   // vote dim 0..15  (p = d>>2, r = d&3)
  const int kg = lane >> 4;  // k-group 0..3 ; lane owns k = kg + 4*j
  const int p_i = d >> 2;
  const int r_i = d & 3;
  const float inv_temp = (MODE == 0) ? 0.0005f : (MODE == 1) ? 0.000975f : 0.00142625f;

  float vreg[36];

  for (int t = 0; t < 4; ++t) {
    const int o = wv * 4 + t;
    // votes: v[k][p][r] = sum_q pose[k][p][q] * w[k][o][q][r]
#pragma unroll
    for (int j = 0; j < 36; ++j) {
      const int k = kg + 4 * j;
      const float* pk = pose_s + k * 16 + p_i * 4;
      const float* wk = w + (size_t)(k * 16 + o) * 16 + r_i;
      vreg[j] = pk[0] * wk[0] + pk[1] * wk[4] + pk[2] * wk[8] + pk[3] * wk[12];
    }
    // rr_sum and mean
    float s_rr = 0.f, s_mv = 0.f;
#pragma unroll
    for (int j = 0; j < 36; ++j) {
      const int k = kg + 4 * j;
      const float rp = rr_s[k * 16 + o];
      s_rr += rp;
      s_mv += rp * vreg[j];
    }
    s_rr += __shfl_xor(s_rr, 16); s_rr += __shfl_xor(s_rr, 32);
    s_mv += __shfl_xor(s_mv, 16); s_mv += __shfl_xor(s_mv, 32);
    const float rsum = s_rr + EPS_;
    const float mean = s_mv / rsum;
    // variance
    float s_var = 0.f;
#pragma unroll
    for (int j = 0; j < 36; ++j) {
      const int k = kg + 4 * j;
      const float rp = rr_s[k * 16 + o];
      const float dv = vreg[j] - mean;
      s_var += rp * dv * dv;
    }
    s_var += __shfl_xor(s_var, 16); s_var += __shfl_xor(s_var, 32);
    const float var = s_var / rsum + EPS_;
    // cost -> act_j
    float slv = __logf(var);
    slv += __shfl_xor(slv, 1); slv += __shfl_xor(slv, 2);
    slv += __shfl_xor(slv, 4); slv += __shfl_xor(slv, 8);
    const float cost = (16.0f * beta_v[o] + 0.5f * slv) * rsum;
    const float aj = 1.0f / (1.0f + __expf(-inv_temp * (beta_a[o] - cost)));

    if (MODE == 2) {
      if (kg == 0) out[(size_t)(bid * 16 + o) * 16 + d] = mean;
      if (lane == 0) out[(size_t)B_ * P2_ * O_ * 16 + bid * 16 + o] = aj;
    } else {
      const float logdet = slv + 16.0f * LOG2PI_;
      const float la = __logf(aj + EPS_);
      const float iv = 1.0f / var;
#pragma unroll
      for (int j = 0; j < 36; ++j) {
        const int k = kg + 4 * j;
        const float dv = vreg[j] - mean;
        float q = dv * dv * iv;
        q += __shfl_xor(q, 1); q += __shfl_xor(q, 2);
        q += __shfl_xor(q, 4); q += __shfl_xor(q, 8);
        if (d == 0) rr_s[k * 16 + o] = la - 0.5f * (q + logdet);  // z[k][o]
      }
    }
  }

  if (MODE != 2) {
    __syncthreads();
    float* zo = zout + (size_t)bid * NV_;
    for (int idx = tid; idx < NV_; idx += 256) zo[idx] = rr_s[idx];
  }
}

// per-(b,h,w,ci) segment max + sum(exp) over covering (patch, kk) x O entries
__global__ __launch_bounds__(256) void seg_reduce(const float* __restrict__ z,
                                                  float* __restrict__ gmax,
                                                  float* __restrict__ gden) {
  const int tid = blockIdx.x * 256 + threadIdx.x;  // 0..32767
  const int ci = tid & 15;
  const int w2 = (tid >> 4) & 15;
  const int h = (tid >> 8) & 15;
  const int b = tid >> 12;
  float m = -3.0e38f;
  for (int ki = 0; ki < 3; ++ki) {
    const int pi = h - ki;
    if ((unsigned)pi >= (unsigned)P_) continue;
    for (int kj = 0; kj < 3; ++kj) {
      const int pj = w2 - kj;
      if ((unsigned)pj >= (unsigned)P_) continue;
      const float* zp =
          z + (size_t)((b * P2_ + pi * P_ + pj) * K2CI_ + (ki * 3 + kj) * CI_ + ci) * 16;
#pragma unroll
      for (int o = 0; o < 16; ++o) m = fmaxf(m, zp[o]);
    }
  }
  float s = 0.f;
  for (int ki = 0; ki < 3; ++ki) {
    const int pi = h - ki;
    if ((unsigned)pi >= (unsigned)P_) continue;
    for (int kj = 0; kj < 3; ++kj) {
      const int pj = w2 - kj;
      if ((unsigned)pj >= (unsigned)P_) continue;
      const float* zp =
          z + (size_t)((b * P2_ + pi * P_ + pj) * K2CI_ + (ki * 3 + kj) * CI_ + ci) * 16;
#pragma unroll
      for (int o = 0; o < 16; ++o) s += __expf(zp[o] - m);
    }
  }
  gmax[tid] = m;
  gden[tid] = s;
}
}  // namespace

extern "C" void kernel_launch(void* const* d_in, const int* in_sizes, int n_in,
                              void* d_out, int out_size, void* d_ws, size_t ws_size,
                              hipStream_t stream) {
  const float* pose = (const float*)d_in[0];
  const float* act = (const float*)d_in[1];
  const float* w = (const float*)d_in[2];
  const float* ba = (const float*)d_in[3];
  const float* bv = (const float*)d_in[4];
  float* out = (float*)d_out;

  float* z = (float*)d_ws;                       // 3,612,672 floats
  float* gm = z + (size_t)B_ * P2_ * NV_;        // 32,768 floats
  float* gd = gm + B_ * H_ * H_ * CI_;           // 32,768 floats

  const int NB = B_ * P2_;  // 1568 blocks
  caps_main<0><<<NB, 256, 0, stream>>>(pose, act, w, ba, bv, z, gm, gd, z, out);
  seg_reduce<<<(B_ * H_ * H_ * CI_) / 256, 256, 0, stream>>>(z, gm, gd);
  caps_main<1><<<NB, 256, 0, stream>>>(pose, act, w, ba, bv, z, gm, gd, z, out);
  seg_reduce<<<(B_ * H_ * H_ * CI_) / 256, 256, 0, stream>>>(z, gm, gd);
  caps_main<2><<<NB, 256, 0, stream>>>(pose, act, w, ba, bv, z, gm, gd, z, out);
}

// Round 2
// 344.418 us; speedup vs baseline: 3.4461x; 3.4461x over previous
//
#include <hip/hip_runtime.h>

namespace {
constexpr int B_ = 8, H_ = 16, CI_ = 16, O_ = 16, P_ = 14;
constexpr int P2_ = P_ * P_;            // 196
constexpr int K2CI_ = 9 * CI_;          // 144
constexpr int NV_ = K2CI_ * O_;         // 2304
constexpr int SLAB_ST_ = 17;            // padded slab row stride (bank-conflict-free)
constexpr float EPS_ = 1e-9f;
constexpr float LOG2PI_ = 1.8378770664093453f;

__device__ __forceinline__ float cnt1(int h) {
  int lo = (h - (P_ - 1)) > 0 ? (h - (P_ - 1)) : 0;
  int hi = h < 2 ? h : 2;
  return (float)(hi - lo + 1);
}

// wt[k][o][r][q] = w[k][o][q][r]  -> vote inner product becomes one dwordx4
__global__ __launch_bounds__(256) void transpose_w(const float* __restrict__ w,
                                                   float* __restrict__ wt) {
  const int i = blockIdx.x * 256 + threadIdx.x;  // 0..36863
  const int ko = i >> 4;
  const int q = (i >> 2) & 3;
  const int r = i & 3;
  wt[(ko << 4) + (r << 2) + q] = w[i];
}

// MODE 0: rr uniform, write z.  MODE 1: rr from softmax, write z.  MODE 2: rr from softmax, write outputs.
template <int MODE>
__global__ __launch_bounds__(256) void caps_main(
    const float* __restrict__ pose, const float* __restrict__ act,
    const float* __restrict__ wt, const float* __restrict__ beta_a,
    const float* __restrict__ beta_v, const float* __restrict__ zin,
    const float* __restrict__ gmax, const float* __restrict__ gden,
    float* __restrict__ zout, float* __restrict__ out) {
  __shared__ float pose_s[K2CI_ * 16];            // 9216 B
  __shared__ float act_s[K2CI_];                  //  576 B
  __shared__ float rr_s[NV_];                     // rr'[o*144+k] ; 9216 B
  __shared__ float slab[4][K2CI_ * SLAB_ST_];     // votes v[k][d], per wave ; 39168 B
  __shared__ float mstat[4][2][16];               // mean, inv-var per wave ; 512 B

  const int bid = blockIdx.x;
  const int b = bid / P2_;
  const int p2 = bid % P2_;
  const int pi = p2 / P_;
  const int pj = p2 % P_;
  const int tid = threadIdx.x;

  // ---- stage pose patch + activations (float4 rows) ----
  for (int ki = 0; ki < 3; ++ki) {
    const float4* src = (const float4*)(pose + (size_t)((b * H_ + pi + ki) * H_ + pj) * CI_ * 16);
    if (tid < 192) ((float4*)&pose_s[ki * 768])[tid] = src[tid];
    const float* asrc = act + (size_t)((b * H_ + pi + ki) * H_ + pj) * CI_;
    if (tid < 48) act_s[ki * 48 + tid] = asrc[tid];
  }
  __syncthreads();

  // ---- stage rr'[o][k] = rr[k][o] * act_i[k] ----
  for (int idx = tid; idx < NV_; idx += 256) {
    const int o_ = idx / K2CI_;
    const int k = idx - o_ * K2CI_;
    const int kk = k >> 4;
    const int ki = kk / 3, kj = kk - 3 * ki;
    const int h = pi + ki, w2 = pj + kj;
    float val;
    if (MODE == 0) {
      val = act_s[k] / (16.0f * cnt1(h) * cnt1(w2));
    } else {
      const float zv = zin[(size_t)bid * NV_ + idx];
      const int cidx = ((b * H_ + h) * H_ + w2) * CI_ + (k & 15);
      const float rr = __expf(zv - gmax[cidx]) / (gden[cidx] + EPS_);
      val = rr * act_s[k];
    }
    rr_s[idx] = val;
  }
  __syncthreads();

  // ---- per-wave: 4 output capsules; lane = kg*16 + d ----
  const int lane = tid & 63;
  const int wv = tid >> 6;
  const int d = lane & 15;
  const int kg = lane >> 4;
  const int p_i = d >> 2;
  const int r_i = d & 3;
  const float inv_temp = (MODE == 0) ? 0.0005f : (MODE == 1) ? 0.000975f : 0.00142625f;

  float vreg[36], rreg[36];

  for (int t = 0; t < 4; ++t) {
    const int o = wv * 4 + t;
    // votes: v[k][d] = dot(pose_s[k][p_i][0..3], wt[k][o][r_i][0..3])
#pragma unroll
    for (int j = 0; j < 36; ++j) {
      const int k = kg + 4 * j;
      const float4 pk = *(const float4*)(pose_s + k * 16 + p_i * 4);
      const float4 wk = *(const float4*)(wt + (size_t)((k * 16 + o) * 16 + r_i * 4));
      vreg[j] = pk.x * wk.x + pk.y * wk.y + pk.z * wk.z + pk.w * wk.w;
      rreg[j] = rr_s[o * K2CI_ + k];
    }
    // rr_sum and mean (reduce over kg via xor16/32)
    float s_rr = 0.f, s_mv = 0.f;
#pragma unroll
    for (int j = 0; j < 36; ++j) {
      s_rr += rreg[j];
      s_mv += rreg[j] * vreg[j];
    }
    s_rr += __shfl_xor(s_rr, 16); s_rr += __shfl_xor(s_rr, 32);
    s_mv += __shfl_xor(s_mv, 16); s_mv += __shfl_xor(s_mv, 32);
    const float rsum = s_rr + EPS_;
    const float mean = s_mv / rsum;
    // variance + stash votes to slab
    float s_var = 0.f;
#pragma unroll
    for (int j = 0; j < 36; ++j) {
      const int k = kg + 4 * j;
      const float dv = vreg[j] - mean;
      s_var += rreg[j] * dv * dv;
      if (MODE != 2) slab[wv][k * SLAB_ST_ + d] = vreg[j];
    }
    s_var += __shfl_xor(s_var, 16); s_var += __shfl_xor(s_var, 32);
    const float var = s_var / rsum + EPS_;
    // cost -> act_j  (reduce log var over d via xor 1/2/4/8)
    float slv = __logf(var);
    slv += __shfl_xor(slv, 1); slv += __shfl_xor(slv, 2);
    slv += __shfl_xor(slv, 4); slv += __shfl_xor(slv, 8);
    const float cost = (16.0f * beta_v[o] + 0.5f * slv) * rsum;
    const float aj = 1.0f / (1.0f + __expf(-inv_temp * (beta_a[o] - cost)));

    if (MODE == 2) {
      if (kg == 0) out[(size_t)(bid * 16 + o) * 16 + d] = mean;
      if (lane == 0) out[(size_t)B_ * P2_ * O_ * 16 + bid * 16 + o] = aj;
    } else {
      // publish per-d stats, then lanes switch to one-k-per-lane for z
      if (kg == 0) {
        mstat[wv][0][d] = mean;
        mstat[wv][1][d] = 1.0f / var;
      }
      __builtin_amdgcn_wave_barrier();
      float mreg[16], ivreg[16];
#pragma unroll
      for (int dd = 0; dd < 16; ++dd) {
        mreg[dd] = mstat[wv][0][dd];
        ivreg[dd] = mstat[wv][1][dd];
      }
      const float Cz = __logf(aj + EPS_) - 0.5f * (slv + 16.0f * LOG2PI_);
      for (int k = lane; k < K2CI_; k += 64) {
        float q = 0.f;
#pragma unroll
        for (int dd = 0; dd < 16; ++dd) {
          const float dv = slab[wv][k * SLAB_ST_ + dd] - mreg[dd];
          q += dv * dv * ivreg[dd];
        }
        zout[(size_t)bid * NV_ + o * K2CI_ + k] = Cz - 0.5f * q;
      }
      __builtin_amdgcn_wave_barrier();
    }
  }
}

// per-(b,h,w,ci): segment max + sum(exp) over covering patches x O, z layout [bid][o*144+kk*16+ci]
__global__ __launch_bounds__(256) void seg_reduce(const float* __restrict__ z,
                                                  float* __restrict__ gmax,
                                                  float* __restrict__ gden) {
  const int tid = blockIdx.x * 256 + threadIdx.x;  // 0..32767
  const int ci = tid & 15;
  const int w2 = (tid >> 4) & 15;
  const int h = (tid >> 8) & 15;
  const int b = tid >> 12;
  float m = -3.0e38f;
  for (int ki = 0; ki < 3; ++ki) {
    const int pi = h - ki;
    if ((unsigned)pi >= (unsigned)P_) continue;
    for (int kj = 0; kj < 3; ++kj) {
      const int pj = w2 - kj;
      if ((unsigned)pj >= (unsigned)P_) continue;
      const float* zp = z + (size_t)(b * P2_ + pi * P_ + pj) * NV_ + (ki * 3 + kj) * CI_ + ci;
#pragma unroll
      for (int o = 0; o < 16; ++o) m = fmaxf(m, zp[o * K2CI_]);
    }
  }
  float s = 0.f;
  for (int ki = 0; ki < 3; ++ki) {
    const int pi = h - ki;
    if ((unsigned)pi >= (unsigned)P_) continue;
    for (int kj = 0; kj < 3; ++kj) {
      const int pj = w2 - kj;
      if ((unsigned)pj >= (unsigned)P_) continue;
      const float* zp = z + (size_t)(b * P2_ + pi * P_ + pj) * NV_ + (ki * 3 + kj) * CI_ + ci;
#pragma unroll
      for (int o = 0; o < 16; ++o) s += __expf(zp[o * K2CI_] - m);
    }
  }
  gmax[tid] = m;
  gden[tid] = s;
}
}  // namespace

extern "C" void kernel_launch(void* const* d_in, const int* in_sizes, int n_in,
                              void* d_out, int out_size, void* d_ws, size_t ws_size,
                              hipStream_t stream) {
  const float* pose = (const float*)d_in[0];
  const float* act = (const float*)d_in[1];
  const float* w = (const float*)d_in[2];
  const float* ba = (const float*)d_in[3];
  const float* bv = (const float*)d_in[4];
  float* out = (float*)d_out;

  float* z = (float*)d_ws;                         // 3,612,672 floats
  float* gm = z + (size_t)B_ * P2_ * NV_;          // 32,768
  float* gd = gm + B_ * H_ * H_ * CI_;             // 32,768
  float* wt = gd + B_ * H_ * H_ * CI_;             // 36,864

  transpose_w<<<144, 256, 0, stream>>>(w, wt);
  const int NB = B_ * P2_;  // 1568
  caps_main<0><<<NB, 256, 0, stream>>>(pose, act, wt, ba, bv, z, gm, gd, z, out);
  seg_reduce<<<(B_ * H_ * H_ * CI_) / 256, 256, 0, stream>>>(z, gm, gd);
  caps_main<1><<<NB, 256, 0, stream>>>(pose, act, wt, ba, bv, z, gm, gd, z, out);
  seg_reduce<<<(B_ * H_ * H_ * CI_) / 256, 256, 0, stream>>>(z, gm, gd);
  caps_main<2><<<NB, 256, 0, stream>>>(pose, act, wt, ba, bv, z, gm, gd, z, out);
}

// Round 3
// 273.435 us; speedup vs baseline: 4.3407x; 1.2596x over previous
//
#include <hip/hip_runtime.h>

namespace {
constexpr int B_ = 8, H_ = 16, CI_ = 16, O_ = 16, P_ = 14;
constexpr int P2_ = P_ * P_;            // 196
constexpr int K2CI_ = 9 * CI_;          // 144
constexpr int NV_ = K2CI_ * O_;         // 2304
constexpr float EPS_ = 1e-9f;
constexpr float LOG2PI_ = 1.8378770664093453f;

__device__ __forceinline__ float cnt1(int h) {
  int lo = (h - (P_ - 1)) > 0 ? (h - (P_ - 1)) : 0;
  int hi = h < 2 ? h : 2;
  return (float)(hi - lo + 1);
}

// wt[k][o][r][q] = w[k][o][q][r]
__global__ __launch_bounds__(256) void transpose_w(const float* __restrict__ w,
                                                   float* __restrict__ wt) {
  const int i = blockIdx.x * 256 + threadIdx.x;  // 0..36863
  const int ko = i >> 4;
  const int q = (i >> 2) & 3;
  const int r = i & 3;
  wt[(ko << 4) + (r << 2) + q] = w[i];
}

// MODE 0: rr uniform, write z.  MODE 1: rr from softmax, write z.  MODE 2: rr from softmax, write outputs.
template <int MODE>
__global__ __launch_bounds__(256, 3) void caps_main(
    const float* __restrict__ pose, const float* __restrict__ act,
    const float* __restrict__ wt, const float* __restrict__ beta_a,
    const float* __restrict__ beta_v, const float* __restrict__ zin,
    const float* __restrict__ gmax, const float* __restrict__ gden,
    float* __restrict__ zout, float* __restrict__ out) {
  __shared__ float pose_s[K2CI_ * 16];  // 9216 B
  __shared__ float act_s[K2CI_];        //  576 B
  __shared__ float z_s[NV_];            // z staging [o*144+k] ; 9216 B (elided in MODE 2)

  const int bid = blockIdx.x;
  const int b = bid / P2_;
  const int p2 = bid % P2_;
  const int pi = p2 / P_;
  const int pj = p2 % P_;
  const int tid = threadIdx.x;

  // ---- stage pose patch + activations ----
  for (int ki = 0; ki < 3; ++ki) {
    const float4* src = (const float4*)(pose + (size_t)((b * H_ + pi + ki) * H_ + pj) * CI_ * 16);
    if (tid < 192) ((float4*)&pose_s[ki * 768])[tid] = src[tid];
    const float* asrc = act + (size_t)((b * H_ + pi + ki) * H_ + pj) * CI_;
    if (tid < 48) act_s[ki * 48 + tid] = asrc[tid];
  }
  __syncthreads();

  // lane owns: k = kk16 + 16*j (j=0..8), vote dims d = dg*4 + r (r=0..3), pose row p = dg
  const int lane = tid & 63;
  const int wv = tid >> 6;
  const int kk16 = lane >> 2;
  const int dg = lane & 3;
  const float inv_temp = (MODE == 0) ? 0.0005f : (MODE == 1) ? 0.000975f : 0.00142625f;

  // ---- hoisted t-invariant per-j state ----
  float4 preg[9];
  float aa[9];   // MODE0: rr'[k] directly ; MODE1: act/(den)
  float am[9];   // MODE1: gmax
#pragma unroll
  for (int j = 0; j < 9; ++j) {
    const int k = kk16 + 16 * j;
    preg[j] = *(const float4*)(pose_s + k * 16 + dg * 4);
    const int ki = j / 3, kj = j - 3 * ki;
    if (MODE == 0) {
      aa[j] = act_s[k] / (16.0f * cnt1(pi + ki) * cnt1(pj + kj));
      am[j] = 0.f;
    } else {
      const int cidx = ((b * H_ + pi + ki) * H_ + pj + kj) * CI_ + kk16;
      am[j] = gmax[cidx];
      aa[j] = act_s[k] / (gden[cidx] + EPS_);
    }
  }

  for (int t = 0; t < 4; ++t) {
    const int o = wv * 4 + t;
    float v[9][4], rreg[9];
#pragma unroll
    for (int j = 0; j < 9; ++j) {
      const int k = kk16 + 16 * j;
      const float4* wb = (const float4*)(wt + (size_t)((k * 16 + o) << 4));
      const float4 w0 = wb[0], w1 = wb[1], w2 = wb[2], w3 = wb[3];
      const float4 p = preg[j];
      v[j][0] = p.x * w0.x + p.y * w0.y + p.z * w0.z + p.w * w0.w;
      v[j][1] = p.x * w1.x + p.y * w1.y + p.z * w1.z + p.w * w1.w;
      v[j][2] = p.x * w2.x + p.y * w2.y + p.z * w2.z + p.w * w2.w;
      v[j][3] = p.x * w3.x + p.y * w3.y + p.z * w3.z + p.w * w3.w;
      if (MODE == 0) {
        rreg[j] = aa[j];
      } else {
        rreg[j] = __expf(zin[(size_t)bid * NV_ + o * K2CI_ + k] - am[j]) * aa[j];
      }
    }
    // rr_sum + per-d mean partials; reduce over kk16 (xor 4/8/16/32)
    float prr = 0.f, pm0 = 0.f, pm1 = 0.f, pm2 = 0.f, pm3 = 0.f;
#pragma unroll
    for (int j = 0; j < 9; ++j) {
      prr += rreg[j];
      pm0 += rreg[j] * v[j][0];
      pm1 += rreg[j] * v[j][1];
      pm2 += rreg[j] * v[j][2];
      pm3 += rreg[j] * v[j][3];
    }
#pragma unroll
    for (int m = 4; m <= 32; m <<= 1) {
      prr += __shfl_xor(prr, m);
      pm0 += __shfl_xor(pm0, m);
      pm1 += __shfl_xor(pm1, m);
      pm2 += __shfl_xor(pm2, m);
      pm3 += __shfl_xor(pm3, m);
    }
    const float rsum = prr + EPS_;
    const float inv_rsum = 1.0f / rsum;
    float mean[4] = {pm0 * inv_rsum, pm1 * inv_rsum, pm2 * inv_rsum, pm3 * inv_rsum};
    // variance
    float pv0 = 0.f, pv1 = 0.f, pv2 = 0.f, pv3 = 0.f;
#pragma unroll
    for (int j = 0; j < 9; ++j) {
      float d0 = v[j][0] - mean[0], d1 = v[j][1] - mean[1];
      float d2 = v[j][2] - mean[2], d3 = v[j][3] - mean[3];
      pv0 += rreg[j] * d0 * d0;
      pv1 += rreg[j] * d1 * d1;
      pv2 += rreg[j] * d2 * d2;
      pv3 += rreg[j] * d3 * d3;
    }
#pragma unroll
    for (int m = 4; m <= 32; m <<= 1) {
      pv0 += __shfl_xor(pv0, m);
      pv1 += __shfl_xor(pv1, m);
      pv2 += __shfl_xor(pv2, m);
      pv3 += __shfl_xor(pv3, m);
    }
    float var[4] = {pv0 * inv_rsum + EPS_, pv1 * inv_rsum + EPS_,
                    pv2 * inv_rsum + EPS_, pv3 * inv_rsum + EPS_};
    // sum of log var over all 16 d: in-lane 4 + xor over dg (1/2)
    float slv = __logf(var[0]) + __logf(var[1]) + __logf(var[2]) + __logf(var[3]);
    slv += __shfl_xor(slv, 1);
    slv += __shfl_xor(slv, 2);
    const float cost = (16.0f * beta_v[o] + 0.5f * slv) * rsum;
    const float aj = 1.0f / (1.0f + __expf(-inv_temp * (beta_a[o] - cost)));

    if (MODE == 2) {
      if (kk16 == 0) {
        *(float4*)(out + (size_t)(bid * 16 + o) * 16 + dg * 4) =
            make_float4(mean[0], mean[1], mean[2], mean[3]);
      }
      if (lane == 0) out[(size_t)B_ * P2_ * O_ * 16 + bid * 16 + o] = aj;
    } else {
      const float iv0 = 1.0f / var[0], iv1 = 1.0f / var[1];
      const float iv2 = 1.0f / var[2], iv3 = 1.0f / var[3];
      const float Cz = __logf(aj + EPS_) - 0.5f * (slv + 16.0f * LOG2PI_);
#pragma unroll
      for (int j = 0; j < 9; ++j) {
        float d0 = v[j][0] - mean[0], d1 = v[j][1] - mean[1];
        float d2 = v[j][2] - mean[2], d3 = v[j][3] - mean[3];
        float q = d0 * d0 * iv0 + d1 * d1 * iv1 + d2 * d2 * iv2 + d3 * d3 * iv3;
        q += __shfl_xor(q, 1);
        q += __shfl_xor(q, 2);
        if (dg == (j & 3)) z_s[o * K2CI_ + kk16 + 16 * j] = Cz - 0.5f * q;
      }
    }
  }

  if (MODE != 2) {
    __syncthreads();
    float4* zo = (float4*)(zout + (size_t)bid * NV_);
    const float4* zs = (const float4*)z_s;
    for (int i = tid; i < NV_ / 4; i += 256) zo[i] = zs[i];
  }
}

// per-(b,h,w,ci): segment max + sum(exp); z layout [bid][o*144 + kk*16 + ci]
__global__ __launch_bounds__(256) void seg_reduce(const float* __restrict__ z,
                                                  float* __restrict__ gmax,
                                                  float* __restrict__ gden) {
  const int tid = blockIdx.x * 256 + threadIdx.x;  // 0..32767
  const int ci = tid & 15;
  const int w2 = (tid >> 4) & 15;
  const int h = (tid >> 8) & 15;
  const int b = tid >> 12;
  float m = -3.0e38f;
  for (int ki = 0; ki < 3; ++ki) {
    const int pi = h - ki;
    if ((unsigned)pi >= (unsigned)P_) continue;
    for (int kj = 0; kj < 3; ++kj) {
      const int pj = w2 - kj;
      if ((unsigned)pj >= (unsigned)P_) continue;
      const float* zp = z + (size_t)(b * P2_ + pi * P_ + pj) * NV_ + (ki * 3 + kj) * CI_ + ci;
#pragma unroll
      for (int o = 0; o < 16; ++o) m = fmaxf(m, zp[o * K2CI_]);
    }
  }
  float s = 0.f;
  for (int ki = 0; ki < 3; ++ki) {
    const int pi = h - ki;
    if ((unsigned)pi >= (unsigned)P_) continue;
    for (int kj = 0; kj < 3; ++kj) {
      const int pj = w2 - kj;
      if ((unsigned)pj >= (unsigned)P_) continue;
      const float* zp = z + (size_t)(b * P2_ + pi * P_ + pj) * NV_ + (ki * 3 + kj) * CI_ + ci;
#pragma unroll
      for (int o = 0; o < 16; ++o) s += __expf(zp[o * K2CI_] - m);
    }
  }
  gmax[tid] = m;
  gden[tid] = s;
}
}  // namespace

extern "C" void kernel_launch(void* const* d_in, const int* in_sizes, int n_in,
                              void* d_out, int out_size, void* d_ws, size_t ws_size,
                              hipStream_t stream) {
  const float* pose = (const float*)d_in[0];
  const float* act = (const float*)d_in[1];
  const float* w = (const float*)d_in[2];
  const float* ba = (const float*)d_in[3];
  const float* bv = (const float*)d_in[4];
  float* out = (float*)d_out;

  float* z = (float*)d_ws;                         // 3,612,672 floats
  float* gm = z + (size_t)B_ * P2_ * NV_;          // 32,768
  float* gd = gm + B_ * H_ * H_ * CI_;             // 32,768
  float* wt = gd + B_ * H_ * H_ * CI_;             // 36,864

  transpose_w<<<144, 256, 0, stream>>>(w, wt);
  const int NB = B_ * P2_;  // 1568
  caps_main<0><<<NB, 256, 0, stream>>>(pose, act, wt, ba, bv, z, gm, gd, z, out);
  seg_reduce<<<(B_ * H_ * H_ * CI_) / 256, 256, 0, stream>>>(z, gm, gd);
  caps_main<1><<<NB, 256, 0, stream>>>(pose, act, wt, ba, bv, z, gm, gd, z, out);
  seg_reduce<<<(B_ * H_ * H_ * CI_) / 256, 256, 0, stream>>>(z, gm, gd);
  caps_main<2><<<NB, 256, 0, stream>>>(pose, act, wt, ba, bv, z, gm, gd, z, out);
}

// Round 4
// 265.587 us; speedup vs baseline: 4.4690x; 1.0296x over previous
//
#include <hip/hip_runtime.h>

namespace {
constexpr int B_ = 8, H_ = 16, CI_ = 16, O_ = 16, P_ = 14;
constexpr int P2_ = P_ * P_;    // 196
constexpr int K2CI_ = 144;
constexpr int NV_ = 2304;       // z per patch, layout [k][o]
constexpr float EPS_ = 1e-9f;
constexpr float LOG2PI_ = 1.8378770664093453f;

__device__ __forceinline__ float cnt1(int h) {
  int lo = (h - (P_ - 1)) > 0 ? (h - (P_ - 1)) : 0;
  int hi = h < 2 ? h : 2;
  return (float)(hi - lo + 1);
}

// wt[k][o][r][q] = w[k][o][q][r]
__global__ __launch_bounds__(256) void transpose_w(const float* __restrict__ w,
                                                   float* __restrict__ wt) {
  const int i = blockIdx.x * 256 + threadIdx.x;
  const int ko = i >> 4, q = (i >> 2) & 3, r = i & 3;
  wt[(ko << 4) + (r << 2) + q] = w[i];
}

// One wave per patch. lane = o*4 + r ; lane covers dims d = p*4+r, p=0..3.
// MODE 0: rr uniform -> z. MODE 1: rr softmax -> z. MODE 2: rr softmax -> outputs.
template <int MODE>
__global__ __launch_bounds__(256, 3) void caps_main(
    const float* __restrict__ pose, const float* __restrict__ act,
    const float* __restrict__ wt, const float* __restrict__ beta_a,
    const float* __restrict__ beta_v, const float* __restrict__ zin,
    const float* __restrict__ gmax, const float* __restrict__ gden,
    float* __restrict__ zout, float* __restrict__ out) {
  extern __shared__ float smem[];
  const int tid = threadIdx.x;
  const int wv = tid >> 6, l = tid & 63;
  const int o = l >> 2, r = l & 3;
  const int pid = __builtin_amdgcn_readfirstlane(blockIdx.x * 4 + wv);
  const int b = pid / P2_;
  const int p2 = pid - b * P2_;
  const int pi = p2 / P_;
  const int pj = p2 - pi * P_;
  constexpr int WSTRIDE = (MODE == 0) ? K2CI_ : (NV_ + 2 * K2CI_);
  float* rrW = smem + wv * WSTRIDE;  // MODE0: rr0[144] ; else rr[2304] ([k][o])
  const float inv_temp = (MODE == 0) ? 0.0005f : (MODE == 1) ? 0.000975f : 0.00142625f;

  // ---- prologue: stage rr into LDS (per-wave region; wave-synchronous, no barriers) ----
  if (MODE == 0) {
    for (int idx = l; idx < K2CI_; idx += 64) {
      const int ci = idx & 15, kk = idx >> 4;
      const int ki = (kk >= 6) ? 2 : (kk >= 3) ? 1 : 0, kj = kk - 3 * ki;
      const int cidx = ((b * H_ + pi + ki) * H_ + pj + kj) * CI_ + ci;
      rrW[idx] = act[cidx] / (16.0f * cnt1(pi + ki) * cnt1(pj + kj));
    }
  } else {
    float* gmW = rrW + NV_;
    float* adW = gmW + K2CI_;
    for (int idx = l; idx < K2CI_; idx += 64) {
      const int ci = idx & 15, kk = idx >> 4;
      const int ki = (kk >= 6) ? 2 : (kk >= 3) ? 1 : 0, kj = kk - 3 * ki;
      const int cidx = ((b * H_ + pi + ki) * H_ + pj + kj) * CI_ + ci;
      gmW[idx] = gmax[cidx];
      adW[idx] = act[cidx] / (gden[cidx] + EPS_);
    }
    __builtin_amdgcn_wave_barrier();
    const float4* z4p = (const float4*)(zin + (size_t)pid * NV_);
#pragma unroll
    for (int it = 0; it < 9; ++it) {
      const int i4 = it * 64 + l;
      const int k = i4 >> 2;
      const float4 z4 = z4p[i4];
      const float gmk = gmW[k], adk = adW[k];
      float4 r4;
      r4.x = __expf(z4.x - gmk) * adk;
      r4.y = __expf(z4.y - gmk) * adk;
      r4.z = __expf(z4.z - gmk) * adk;
      r4.w = __expf(z4.w - gmk) * adk;
      *(float4*)(rrW + 4 * i4) = r4;
    }
  }
  __builtin_amdgcn_wave_barrier();
  const float bvo = 16.0f * beta_v[o];
  const float bao = beta_a[o];

  // ---- pass 1: fused mean+var (Welford via E[v^2]-mean^2), in-lane k-reduction ----
  float prr = 0.f;
  float pm0 = 0.f, pm1 = 0.f, pm2 = 0.f, pm3 = 0.f;
  float pv0 = 0.f, pv1 = 0.f, pv2 = 0.f, pv3 = 0.f;
  const float* wl = wt + (l << 2);
  for (int kk = 0; kk < 9; ++kk) {
    const int ki = (kk >= 6) ? 2 : (kk >= 3) ? 1 : 0, kj = kk - 3 * ki;
    const float* pb = pose + ((size_t)((b * H_ + pi + ki) * H_ + pj + kj) << 8);
#pragma unroll 4
    for (int ci = 0; ci < 16; ++ci) {
      const int k = kk * 16 + ci;
      const float4 w4 = *(const float4*)(wl + (k << 8));
      const float4 Pa = *(const float4*)(pb + ci * 16);
      const float4 Pb = *(const float4*)(pb + ci * 16 + 4);
      const float4 Pc = *(const float4*)(pb + ci * 16 + 8);
      const float4 Pd = *(const float4*)(pb + ci * 16 + 12);
      const float v0 = Pa.x * w4.x + Pa.y * w4.y + Pa.z * w4.z + Pa.w * w4.w;
      const float v1 = Pb.x * w4.x + Pb.y * w4.y + Pb.z * w4.z + Pb.w * w4.w;
      const float v2 = Pc.x * w4.x + Pc.y * w4.y + Pc.z * w4.z + Pc.w * w4.w;
      const float v3 = Pd.x * w4.x + Pd.y * w4.y + Pd.z * w4.z + Pd.w * w4.w;
      const float rrk = (MODE == 0) ? rrW[k] : rrW[(k << 4) + o];
      prr += rrk;
      const float a0 = rrk * v0, a1 = rrk * v1, a2 = rrk * v2, a3 = rrk * v3;
      pm0 += a0; pm1 += a1; pm2 += a2; pm3 += a3;
      pv0 = fmaf(a0, v0, pv0); pv1 = fmaf(a1, v1, pv1);
      pv2 = fmaf(a2, v2, pv2); pv3 = fmaf(a3, v3, pv3);
    }
  }
  const float rsum = prr + EPS_;
  const float irs = 1.0f / rsum;
  const float m0 = pm0 * irs, m1 = pm1 * irs, m2 = pm2 * irs, m3 = pm3 * irs;
  const float va0 = fmaxf(pv0 * irs - m0 * m0, 0.f) + EPS_;
  const float va1 = fmaxf(pv1 * irs - m1 * m1, 0.f) + EPS_;
  const float va2 = fmaxf(pv2 * irs - m2 * m2, 0.f) + EPS_;
  const float va3 = fmaxf(pv3 * irs - m3 * m3, 0.f) + EPS_;
  float slv = __logf(va0) + __logf(va1) + __logf(va2) + __logf(va3);
  slv += __shfl_xor(slv, 1);
  slv += __shfl_xor(slv, 2);
  const float cost = (bvo + 0.5f * slv) * rsum;
  const float aj = 1.0f / (1.0f + __expf(-inv_temp * (bao - cost)));

  if (MODE == 2) {
    float* ob = out + ((size_t)(pid * 16 + o) << 4) + r;
    ob[0] = m0; ob[4] = m1; ob[8] = m2; ob[12] = m3;
    if (r == 0) out[(size_t)B_ * P2_ * O_ * 16 + pid * 16 + o] = aj;
    return;
  }

  // ---- pass 2: z[k][o] = log(aj+eps) - 0.5*(q + slv + 16*log(2pi)) ----
  const float iv0 = 1.0f / va0, iv1 = 1.0f / va1, iv2 = 1.0f / va2, iv3 = 1.0f / va3;
  const float Cz = __logf(aj + EPS_) - 0.5f * (slv + 16.0f * LOG2PI_);
  float* zo = zout + (size_t)pid * NV_;
  for (int kk = 0; kk < 9; ++kk) {
    const int ki = (kk >= 6) ? 2 : (kk >= 3) ? 1 : 0, kj = kk - 3 * ki;
    const float* pb = pose + ((size_t)((b * H_ + pi + ki) * H_ + pj + kj) << 8);
#pragma unroll 4
    for (int ci = 0; ci < 16; ++ci) {
      const int k = kk * 16 + ci;
      const float4 w4 = *(const float4*)(wl + (k << 8));
      const float4 Pa = *(const float4*)(pb + ci * 16);
      const float4 Pb = *(const float4*)(pb + ci * 16 + 4);
      const float4 Pc = *(const float4*)(pb + ci * 16 + 8);
      const float4 Pd = *(const float4*)(pb + ci * 16 + 12);
      const float v0 = Pa.x * w4.x + Pa.y * w4.y + Pa.z * w4.z + Pa.w * w4.w;
      const float v1 = Pb.x * w4.x + Pb.y * w4.y + Pb.z * w4.z + Pb.w * w4.w;
      const float v2 = Pc.x * w4.x + Pc.y * w4.y + Pc.z * w4.z + Pc.w * w4.w;
      const float v3 = Pd.x * w4.x + Pd.y * w4.y + Pd.z * w4.z + Pd.w * w4.w;
      const float d0 = v0 - m0, d1 = v1 - m1, d2 = v2 - m2, d3 = v3 - m3;
      float q = d0 * d0 * iv0 + d1 * d1 * iv1 + d2 * d2 * iv2 + d3 * d3 * iv3;
      q += __shfl_xor(q, 1);
      q += __shfl_xor(q, 2);
      if (r == 0) zo[(k << 4) + o] = Cz - 0.5f * q;  // 16 lanes -> one 64B line
    }
  }
}

// 4 threads per segment (b,h,w,ci); z cached in registers between max and sum.
__global__ __launch_bounds__(256) void seg_reduce(const float* __restrict__ z,
                                                  float* __restrict__ gmax,
                                                  float* __restrict__ gden) {
  const int tid = blockIdx.x * 256 + threadIdx.x;  // 0..131071
  const int part = tid & 3, ci = (tid >> 2) & 15, w2 = (tid >> 6) & 15;
  const int h = (tid >> 10) & 15, b = tid >> 14;
  float4 v[9];
  float m = -3.0e38f;
#pragma unroll
  for (int s = 0; s < 9; ++s) {
    const int ki = (s >= 6) ? 2 : (s >= 3) ? 1 : 0, kj = s - 3 * ki;
    const int pi = h - ki, pj = w2 - kj;
    if ((unsigned)pi < (unsigned)P_ && (unsigned)pj < (unsigned)P_) {
      v[s] = *(const float4*)(z + (size_t)(b * P2_ + pi * P_ + pj) * NV_ + s * 256 +
                              ci * 16 + part * 4);
    } else {
      v[s] = make_float4(-3.0e38f, -3.0e38f, -3.0e38f, -3.0e38f);
    }
    m = fmaxf(m, fmaxf(fmaxf(v[s].x, v[s].y), fmaxf(v[s].z, v[s].w)));
  }
  m = fmaxf(m, __shfl_xor(m, 1));
  m = fmaxf(m, __shfl_xor(m, 2));
  float s_ = 0.f;
#pragma unroll
  for (int s = 0; s < 9; ++s) {
    s_ += __expf(v[s].x - m) + __expf(v[s].y - m) + __expf(v[s].z - m) + __expf(v[s].w - m);
  }
  s_ += __shfl_xor(s_, 1);
  s_ += __shfl_xor(s_, 2);
  if (part == 0) {
    gmax[tid >> 2] = m;
    gden[tid >> 2] = s_;
  }
}
}  // namespace

extern "C" void kernel_launch(void* const* d_in, const int* in_sizes, int n_in,
                              void* d_out, int out_size, void* d_ws, size_t ws_size,
                              hipStream_t stream) {
  const float* pose = (const float*)d_in[0];
  const float* act = (const float*)d_in[1];
  const float* w = (const float*)d_in[2];
  const float* ba = (const float*)d_in[3];
  const float* bv = (const float*)d_in[4];
  float* out = (float*)d_out;

  float* z = (float*)d_ws;                  // 3,612,672 floats, layout [pid][k][o]
  float* gm = z + (size_t)B_ * P2_ * NV_;   // 32,768
  float* gd = gm + B_ * H_ * H_ * CI_;      // 32,768
  float* wt = gd + B_ * H_ * H_ * CI_;      // 36,864

  const size_t lds0 = 4 * K2CI_ * sizeof(float);               // 2,304 B
  const size_t lds12 = 4 * (NV_ + 2 * K2CI_) * sizeof(float);  // 41,472 B
  transpose_w<<<144, 256, 0, stream>>>(w, wt);
  caps_main<0><<<392, 256, lds0, stream>>>(pose, act, wt, ba, bv, z, gm, gd, z, out);
  seg_reduce<<<512, 256, 0, stream>>>(z, gm, gd);
  caps_main<1><<<392, 256, lds12, stream>>>(pose, act, wt, ba, bv, z, gm, gd, z, out);
  seg_reduce<<<512, 256, 0, stream>>>(z, gm, gd);
  caps_main<2><<<392, 256, lds12, stream>>>(pose, act, wt, ba, bv, z, gm, gd, z, out);
}

// Round 5
// 225.782 us; speedup vs baseline: 5.2568x; 1.1763x over previous
//
#include <hip/hip_runtime.h>

namespace {
constexpr int B_ = 8, H_ = 16, CI_ = 16, O_ = 16, P_ = 14;
constexpr int P2_ = P_ * P_;    // 196
constexpr int K2CI_ = 144;
constexpr int NV_ = 2304;       // z per patch, layout [k][o]
constexpr float EPS_ = 1e-9f;
constexpr float LOG2PI_ = 1.8378770664093453f;

__device__ __forceinline__ float cnt1(int h) {
  int lo = (h - (P_ - 1)) > 0 ? (h - (P_ - 1)) : 0;
  int hi = h < 2 ? h : 2;
  return (float)(hi - lo + 1);
}

// wt[k][o][r][q] = w[k][o][q][r]
__global__ __launch_bounds__(256) void transpose_w(const float* __restrict__ w,
                                                   float* __restrict__ wt) {
  const int i = blockIdx.x * 256 + threadIdx.x;
  const int ko = i >> 4, q = (i >> 2) & 3, r = i & 3;
  wt[(ko << 4) + (r << 2) + q] = w[i];
}

// One BLOCK per patch; 4 waves split k 4-ways, Welford partials combined in LDS.
// lane = o*4 + r ; lane covers dims d = p*4+r, p=0..3.
// MODE 0: rr uniform -> z. MODE 1: rr softmax -> z. MODE 2: rr softmax -> outputs.
template <int MODE>
__global__ __launch_bounds__(256) void caps_main(
    const float* __restrict__ pose, const float* __restrict__ act,
    const float* __restrict__ wt, const float* __restrict__ beta_a,
    const float* __restrict__ beta_v, const float* __restrict__ zin,
    const float* __restrict__ gmax, const float* __restrict__ gden,
    float* __restrict__ zout, float* __restrict__ out) {
  __shared__ float rr_s[(MODE == 0) ? K2CI_ : NV_];  // MODE0: rr0[k] ; else rr[k][o]
  __shared__ float part[9][256];                     // Welford partials [stat][wv*64+l]
  __shared__ float gm_s[(MODE == 0) ? 1 : K2CI_];
  __shared__ float ad_s[(MODE == 0) ? 1 : K2CI_];

  const int tid = threadIdx.x;
  const int wv = __builtin_amdgcn_readfirstlane(tid >> 6);
  const int l = tid & 63;
  const int o = l >> 2, r = l & 3;
  const int pid = blockIdx.x;
  const int b = pid / P2_;
  const int p2 = pid - b * P2_;
  const int pi = p2 / P_;
  const int pj = p2 - pi * P_;
  const float inv_temp = (MODE == 0) ? 0.0005f : (MODE == 1) ? 0.000975f : 0.00142625f;

  // ---- prologue: stage rr into LDS ----
  if (MODE == 0) {
    if (tid < K2CI_) {
      const int ci = tid & 15, kk = tid >> 4;
      const int ki = (kk >= 6) ? 2 : (kk >= 3) ? 1 : 0, kj = kk - 3 * ki;
      const int cidx = ((b * H_ + pi + ki) * H_ + pj + kj) * CI_ + ci;
      rr_s[tid] = act[cidx] / (16.0f * cnt1(pi + ki) * cnt1(pj + kj));
    }
  } else {
    if (tid < K2CI_) {
      const int ci = tid & 15, kk = tid >> 4;
      const int ki = (kk >= 6) ? 2 : (kk >= 3) ? 1 : 0, kj = kk - 3 * ki;
      const int cidx = ((b * H_ + pi + ki) * H_ + pj + kj) * CI_ + ci;
      gm_s[tid] = gmax[cidx];
      ad_s[tid] = act[cidx] / (gden[cidx] + EPS_);
    }
    __syncthreads();
    const float4* z4p = (const float4*)(zin + (size_t)pid * NV_);
    for (int i4 = tid; i4 < NV_ / 4; i4 += 256) {
      const int k = i4 >> 2;
      const float4 z4 = z4p[i4];
      const float gmk = gm_s[k], adk = ad_s[k];
      float4 r4;
      r4.x = __expf(z4.x - gmk) * adk;
      r4.y = __expf(z4.y - gmk) * adk;
      r4.z = __expf(z4.z - gmk) * adk;
      r4.w = __expf(z4.w - gmk) * adk;
      *(float4*)(rr_s + 4 * i4) = r4;
    }
  }
  __syncthreads();

  const float bvo = 16.0f * beta_v[o];
  const float bao = beta_a[o];
  const float* wl = wt + (l << 2);
  const int k0 = wv * 36;

  // ---- pass 1: fused mean+var partials over this wave's 36 k ----
  float prr = 0.f;
  float pm0 = 0.f, pm1 = 0.f, pm2 = 0.f, pm3 = 0.f;
  float pv0 = 0.f, pv1 = 0.f, pv2 = 0.f, pv3 = 0.f;
#pragma unroll 4
  for (int i = 0; i < 36; ++i) {
    const int k = k0 + i;
    const int kk = k >> 4, ci = k & 15;
    const int ki = (kk >= 6) ? 2 : (kk >= 3) ? 1 : 0, kj = kk - 3 * ki;
    const float* pb = pose + ((size_t)((b * H_ + pi + ki) * H_ + pj + kj) << 8) + (ci << 4);
    const float4 w4 = *(const float4*)(wl + (k << 8));
    const float4 Pa = *(const float4*)(pb);
    const float4 Pb = *(const float4*)(pb + 4);
    const float4 Pc = *(const float4*)(pb + 8);
    const float4 Pd = *(const float4*)(pb + 12);
    const float v0 = Pa.x * w4.x + Pa.y * w4.y + Pa.z * w4.z + Pa.w * w4.w;
    const float v1 = Pb.x * w4.x + Pb.y * w4.y + Pb.z * w4.z + Pb.w * w4.w;
    const float v2 = Pc.x * w4.x + Pc.y * w4.y + Pc.z * w4.z + Pc.w * w4.w;
    const float v3 = Pd.x * w4.x + Pd.y * w4.y + Pd.z * w4.z + Pd.w * w4.w;
    const float rrk = (MODE == 0) ? rr_s[k] : rr_s[(k << 4) + o];
    prr += rrk;
    const float a0 = rrk * v0, a1 = rrk * v1, a2 = rrk * v2, a3 = rrk * v3;
    pm0 += a0; pm1 += a1; pm2 += a2; pm3 += a3;
    pv0 = fmaf(a0, v0, pv0); pv1 = fmaf(a1, v1, pv1);
    pv2 = fmaf(a2, v2, pv2); pv3 = fmaf(a3, v3, pv3);
  }
  // ---- combine partials across waves via LDS (conflict-free layout) ----
  part[0][tid] = prr;
  part[1][tid] = pm0; part[2][tid] = pm1; part[3][tid] = pm2; part[4][tid] = pm3;
  part[5][tid] = pv0; part[6][tid] = pv1; part[7][tid] = pv2; part[8][tid] = pv3;
  __syncthreads();
  float s[9];
#pragma unroll
  for (int j = 0; j < 9; ++j) {
    s[j] = part[j][l] + part[j][64 + l] + part[j][128 + l] + part[j][192 + l];
  }
  const float rsum = s[0] + EPS_;
  const float irs = 1.0f / rsum;
  const float m0 = s[1] * irs, m1 = s[2] * irs, m2 = s[3] * irs, m3 = s[4] * irs;
  const float va0 = fmaxf(s[5] * irs - m0 * m0, 0.f) + EPS_;
  const float va1 = fmaxf(s[6] * irs - m1 * m1, 0.f) + EPS_;
  const float va2 = fmaxf(s[7] * irs - m2 * m2, 0.f) + EPS_;
  const float va3 = fmaxf(s[8] * irs - m3 * m3, 0.f) + EPS_;
  float slv = __logf(va0) + __logf(va1) + __logf(va2) + __logf(va3);
  slv += __shfl_xor(slv, 1);
  slv += __shfl_xor(slv, 2);
  const float cost = (bvo + 0.5f * slv) * rsum;
  const float aj = 1.0f / (1.0f + __expf(-inv_temp * (bao - cost)));

  if (MODE == 2) {
    if (wv == 0) {
      float* ob = out + ((size_t)(pid * 16 + o) << 4) + r;
      ob[0] = m0; ob[4] = m1; ob[8] = m2; ob[12] = m3;
      if (r == 0) out[(size_t)B_ * P2_ * O_ * 16 + pid * 16 + o] = aj;
    }
    return;
  }

  // ---- pass 2: z[k][o] for this wave's 36 k ----
  const float iv0 = 1.0f / va0, iv1 = 1.0f / va1, iv2 = 1.0f / va2, iv3 = 1.0f / va3;
  const float Cz = __logf(aj + EPS_) - 0.5f * (slv + 16.0f * LOG2PI_);
  float* zo = zout + (size_t)pid * NV_;
#pragma unroll 4
  for (int i = 0; i < 36; ++i) {
    const int k = k0 + i;
    const int kk = k >> 4, ci = k & 15;
    const int ki = (kk >= 6) ? 2 : (kk >= 3) ? 1 : 0, kj = kk - 3 * ki;
    const float* pb = pose + ((size_t)((b * H_ + pi + ki) * H_ + pj + kj) << 8) + (ci << 4);
    const float4 w4 = *(const float4*)(wl + (k << 8));
    const float4 Pa = *(const float4*)(pb);
    const float4 Pb = *(const float4*)(pb + 4);
    const float4 Pc = *(const float4*)(pb + 8);
    const float4 Pd = *(const float4*)(pb + 12);
    const float v0 = Pa.x * w4.x + Pa.y * w4.y + Pa.z * w4.z + Pa.w * w4.w;
    const float v1 = Pb.x * w4.x + Pb.y * w4.y + Pb.z * w4.z + Pb.w * w4.w;
    const float v2 = Pc.x * w4.x + Pc.y * w4.y + Pc.z * w4.z + Pc.w * w4.w;
    const float v3 = Pd.x * w4.x + Pd.y * w4.y + Pd.z * w4.z + Pd.w * w4.w;
    const float d0 = v0 - m0, d1 = v1 - m1, d2 = v2 - m2, d3 = v3 - m3;
    float q = d0 * d0 * iv0 + d1 * d1 * iv1 + d2 * d2 * iv2 + d3 * d3 * iv3;
    q += __shfl_xor(q, 1);
    q += __shfl_xor(q, 2);
    if (r == 0) zo[(k << 4) + o] = Cz - 0.5f * q;  // 16 lanes -> one 64B line
  }
}

// 4 threads per segment (b,h,w,ci); z cached in registers between max and sum.
__global__ __launch_bounds__(256) void seg_reduce(const float* __restrict__ z,
                                                  float* __restrict__ gmax,
                                                  float* __restrict__ gden) {
  const int tid = blockIdx.x * 256 + threadIdx.x;  // 0..131071
  const int part = tid & 3, ci = (tid >> 2) & 15, w2 = (tid >> 6) & 15;
  const int h = (tid >> 10) & 15, b = tid >> 14;
  float4 v[9];
  float m = -3.0e38f;
#pragma unroll
  for (int s = 0; s < 9; ++s) {
    const int ki = (s >= 6) ? 2 : (s >= 3) ? 1 : 0, kj = s - 3 * ki;
    const int pi = h - ki, pj = w2 - kj;
    if ((unsigned)pi < (unsigned)P_ && (unsigned)pj < (unsigned)P_) {
      v[s] = *(const float4*)(z + (size_t)(b * P2_ + pi * P_ + pj) * NV_ + s * 256 +
                              ci * 16 + part * 4);
    } else {
      v[s] = make_float4(-3.0e38f, -3.0e38f, -3.0e38f, -3.0e38f);
    }
    m = fmaxf(m, fmaxf(fmaxf(v[s].x, v[s].y), fmaxf(v[s].z, v[s].w)));
  }
  m = fmaxf(m, __shfl_xor(m, 1));
  m = fmaxf(m, __shfl_xor(m, 2));
  float s_ = 0.f;
#pragma unroll
  for (int s = 0; s < 9; ++s) {
    s_ += __expf(v[s].x - m) + __expf(v[s].y - m) + __expf(v[s].z - m) + __expf(v[s].w - m);
  }
  s_ += __shfl_xor(s_, 1);
  s_ += __shfl_xor(s_, 2);
  if (part == 0) {
    gmax[tid >> 2] = m;
    gden[tid >> 2] = s_;
  }
}
}  // namespace

extern "C" void kernel_launch(void* const* d_in, const int* in_sizes, int n_in,
                              void* d_out, int out_size, void* d_ws, size_t ws_size,
                              hipStream_t stream) {
  const float* pose = (const float*)d_in[0];
  const float* act = (const float*)d_in[1];
  const float* w = (const float*)d_in[2];
  const float* ba = (const float*)d_in[3];
  const float* bv = (const float*)d_in[4];
  float* out = (float*)d_out;

  float* z = (float*)d_ws;                  // 3,612,672 floats, layout [pid][k][o]
  float* gm = z + (size_t)B_ * P2_ * NV_;   // 32,768
  float* gd = gm + B_ * H_ * H_ * CI_;      // 32,768
  float* wt = gd + B_ * H_ * H_ * CI_;      // 36,864

  const int NB = B_ * P2_;  // 1568 blocks, one per patch
  transpose_w<<<144, 256, 0, stream>>>(w, wt);
  caps_main<0><<<NB, 256, 0, stream>>>(pose, act, wt, ba, bv, z, gm, gd, z, out);
  seg_reduce<<<512, 256, 0, stream>>>(z, gm, gd);
  caps_main<1><<<NB, 256, 0, stream>>>(pose, act, wt, ba, bv, z, gm, gd, z, out);
  seg_reduce<<<512, 256, 0, stream>>>(z, gm, gd);
  caps_main<2><<<NB, 256, 0, stream>>>(pose, act, wt, ba, bv, z, gm, gd, z, out);
}

// Round 6
// 224.069 us; speedup vs baseline: 5.2970x; 1.0076x over previous
//
#include <hip/hip_runtime.h>

namespace {
constexpr int B_ = 8, H_ = 16, CI_ = 16, O_ = 16, P_ = 14;
constexpr int P2_ = P_ * P_;    // 196
constexpr int K2CI_ = 144;
constexpr int NV_ = 2304;       // z per patch, layout [k][o]
constexpr float EPS_ = 1e-9f;
constexpr float LOG2PI_ = 1.8378770664093453f;

__device__ __forceinline__ float cnt1(int h) {
  int lo = (h - (P_ - 1)) > 0 ? (h - (P_ - 1)) : 0;
  int hi = h < 2 ? h : 2;
  return (float)(hi - lo + 1);
}

// wt[k][o][r][q] = w[k][o][q][r]
__global__ __launch_bounds__(256) void transpose_w(const float* __restrict__ w,
                                                   float* __restrict__ wt) {
  const int i = blockIdx.x * 256 + threadIdx.x;
  const int ko = i >> 4, q = (i >> 2) & 3, r = i & 3;
  wt[(ko << 4) + (r << 2) + q] = w[i];
}

// One BLOCK (512 thr, 8 waves) per patch; waves split k 8-ways (18 each).
// lane = o*4 + r ; lane covers dims d = p*4+r, p=0..3.
// MODE 0: rr uniform -> z. MODE 1: rr softmax -> z. MODE 2: rr softmax -> outputs.
template <int MODE>
__global__ __launch_bounds__(512) void caps_main(
    const float* __restrict__ pose, const float* __restrict__ act,
    const float* __restrict__ wt, const float* __restrict__ beta_a,
    const float* __restrict__ beta_v, const float* __restrict__ zin,
    const float* __restrict__ gmax, const float* __restrict__ gden,
    float* __restrict__ zout, float* __restrict__ out) {
  __shared__ float rr_s[(MODE == 0) ? K2CI_ : NV_];  // MODE0: rr0[k] ; else rr[k][o]
  __shared__ float part[9][512];                     // Welford partials [stat][wv*64+l]
  __shared__ float gm_s[(MODE == 0) ? 1 : K2CI_];
  __shared__ float ad_s[(MODE == 0) ? 1 : K2CI_];

  const int tid = threadIdx.x;
  const int wv = __builtin_amdgcn_readfirstlane(tid >> 6);
  const int l = tid & 63;
  const int o = l >> 2, r = l & 3;
  const int pid = blockIdx.x;
  const int b = pid / P2_;
  const int p2 = pid - b * P2_;
  const int pi = p2 / P_;
  const int pj = p2 - pi * P_;
  const float inv_temp = (MODE == 0) ? 0.0005f : (MODE == 1) ? 0.000975f : 0.00142625f;

  // ---- prologue: stage rr into LDS ----
  if (MODE == 0) {
    if (tid < K2CI_) {
      const int ci = tid & 15, kk = tid >> 4;
      const int ki = (kk >= 6) ? 2 : (kk >= 3) ? 1 : 0, kj = kk - 3 * ki;
      const int cidx = ((b * H_ + pi + ki) * H_ + pj + kj) * CI_ + ci;
      rr_s[tid] = act[cidx] / (16.0f * cnt1(pi + ki) * cnt1(pj + kj));
    }
  } else {
    if (tid < K2CI_) {
      const int ci = tid & 15, kk = tid >> 4;
      const int ki = (kk >= 6) ? 2 : (kk >= 3) ? 1 : 0, kj = kk - 3 * ki;
      const int cidx = ((b * H_ + pi + ki) * H_ + pj + kj) * CI_ + ci;
      gm_s[tid] = gmax[cidx];
      ad_s[tid] = act[cidx] / (gden[cidx] + EPS_);
    }
    __syncthreads();
    const float4* z4p = (const float4*)(zin + (size_t)pid * NV_);
    for (int i4 = tid; i4 < NV_ / 4; i4 += 512) {
      const int k = i4 >> 2;
      const float4 z4 = z4p[i4];
      const float gmk = gm_s[k], adk = ad_s[k];
      float4 r4;
      r4.x = __expf(z4.x - gmk) * adk;
      r4.y = __expf(z4.y - gmk) * adk;
      r4.z = __expf(z4.z - gmk) * adk;
      r4.w = __expf(z4.w - gmk) * adk;
      *(float4*)(rr_s + 4 * i4) = r4;
    }
  }
  __syncthreads();

  const float bvo = 16.0f * beta_v[o];
  const float bao = beta_a[o];
  const float* wl = wt + (l << 2);
  const int k0 = wv * 18;

  // ---- pass 1: fused mean+var partials over this wave's 18 k ----
  float prr = 0.f;
  float pm0 = 0.f, pm1 = 0.f, pm2 = 0.f, pm3 = 0.f;
  float pv0 = 0.f, pv1 = 0.f, pv2 = 0.f, pv3 = 0.f;
#pragma unroll 6
  for (int i = 0; i < 18; ++i) {
    const int k = k0 + i;
    const int kk = k >> 4, ci = k & 15;
    const int ki = (kk >= 6) ? 2 : (kk >= 3) ? 1 : 0, kj = kk - 3 * ki;
    const float* pb = pose + ((size_t)((b * H_ + pi + ki) * H_ + pj + kj) << 8) + (ci << 4);
    const float4 w4 = *(const float4*)(wl + (k << 8));
    const float4 Pa = *(const float4*)(pb);
    const float4 Pb = *(const float4*)(pb + 4);
    const float4 Pc = *(const float4*)(pb + 8);
    const float4 Pd = *(const float4*)(pb + 12);
    const float v0 = Pa.x * w4.x + Pa.y * w4.y + Pa.z * w4.z + Pa.w * w4.w;
    const float v1 = Pb.x * w4.x + Pb.y * w4.y + Pb.z * w4.z + Pb.w * w4.w;
    const float v2 = Pc.x * w4.x + Pc.y * w4.y + Pc.z * w4.z + Pc.w * w4.w;
    const float v3 = Pd.x * w4.x + Pd.y * w4.y + Pd.z * w4.z + Pd.w * w4.w;
    const float rrk = (MODE == 0) ? rr_s[k] : rr_s[(k << 4) + o];
    prr += rrk;
    const float a0 = rrk * v0, a1 = rrk * v1, a2 = rrk * v2, a3 = rrk * v3;
    pm0 += a0; pm1 += a1; pm2 += a2; pm3 += a3;
    pv0 = fmaf(a0, v0, pv0); pv1 = fmaf(a1, v1, pv1);
    pv2 = fmaf(a2, v2, pv2); pv3 = fmaf(a3, v3, pv3);
  }
  // ---- combine partials across 8 waves via LDS (stride-1, conflict-free) ----
  part[0][tid] = prr;
  part[1][tid] = pm0; part[2][tid] = pm1; part[3][tid] = pm2; part[4][tid] = pm3;
  part[5][tid] = pv0; part[6][tid] = pv1; part[7][tid] = pv2; part[8][tid] = pv3;
  __syncthreads();
  float s[9];
#pragma unroll
  for (int j = 0; j < 9; ++j) {
    float acc = part[j][l];
#pragma unroll
    for (int wvi = 1; wvi < 8; ++wvi) acc += part[j][wvi * 64 + l];
    s[j] = acc;
  }
  const float rsum = s[0] + EPS_;
  const float irs = 1.0f / rsum;
  const float m0 = s[1] * irs, m1 = s[2] * irs, m2 = s[3] * irs, m3 = s[4] * irs;
  const float va0 = fmaxf(s[5] * irs - m0 * m0, 0.f) + EPS_;
  const float va1 = fmaxf(s[6] * irs - m1 * m1, 0.f) + EPS_;
  const float va2 = fmaxf(s[7] * irs - m2 * m2, 0.f) + EPS_;
  const float va3 = fmaxf(s[8] * irs - m3 * m3, 0.f) + EPS_;
  float slv = __logf(va0) + __logf(va1) + __logf(va2) + __logf(va3);
  slv += __shfl_xor(slv, 1);
  slv += __shfl_xor(slv, 2);
  const float cost = (bvo + 0.5f * slv) * rsum;
  const float aj = 1.0f / (1.0f + __expf(-inv_temp * (bao - cost)));

  if (MODE == 2) {
    if (wv == 0) {
      float* ob = out + ((size_t)(pid * 16 + o) << 4) + r;
      ob[0] = m0; ob[4] = m1; ob[8] = m2; ob[12] = m3;
      if (r == 0) out[(size_t)B_ * P2_ * O_ * 16 + pid * 16 + o] = aj;
    }
    return;
  }

  // ---- pass 2: z[k][o] for this wave's 18 k ----
  const float iv0 = 1.0f / va0, iv1 = 1.0f / va1, iv2 = 1.0f / va2, iv3 = 1.0f / va3;
  const float Cz = __logf(aj + EPS_) - 0.5f * (slv + 16.0f * LOG2PI_);
  float* zo = zout + (size_t)pid * NV_;
#pragma unroll 6
  for (int i = 0; i < 18; ++i) {
    const int k = k0 + i;
    const int kk = k >> 4, ci = k & 15;
    const int ki = (kk >= 6) ? 2 : (kk >= 3) ? 1 : 0, kj = kk - 3 * ki;
    const float* pb = pose + ((size_t)((b * H_ + pi + ki) * H_ + pj + kj) << 8) + (ci << 4);
    const float4 w4 = *(const float4*)(wl + (k << 8));
    const float4 Pa = *(const float4*)(pb);
    const float4 Pb = *(const float4*)(pb + 4);
    const float4 Pc = *(const float4*)(pb + 8);
    const float4 Pd = *(const float4*)(pb + 12);
    const float v0 = Pa.x * w4.x + Pa.y * w4.y + Pa.z * w4.z + Pa.w * w4.w;
    const float v1 = Pb.x * w4.x + Pb.y * w4.y + Pb.z * w4.z + Pb.w * w4.w;
    const float v2 = Pc.x * w4.x + Pc.y * w4.y + Pc.z * w4.z + Pc.w * w4.w;
    const float v3 = Pd.x * w4.x + Pd.y * w4.y + Pd.z * w4.z + Pd.w * w4.w;
    const float d0 = v0 - m0, d1 = v1 - m1, d2 = v2 - m2, d3 = v3 - m3;
    float q = d0 * d0 * iv0 + d1 * d1 * iv1 + d2 * d2 * iv2 + d3 * d3 * iv3;
    q += __shfl_xor(q, 1);
    q += __shfl_xor(q, 2);
    if (r == 0) zo[(k << 4) + o] = Cz - 0.5f * q;  // 16 lanes -> one 64B line
  }
}

// 4 threads per segment (b,h,w,ci); z cached in registers between max and sum.
__global__ __launch_bounds__(256) void seg_reduce(const float* __restrict__ z,
                                                  float* __restrict__ gmax,
                                                  float* __restrict__ gden) {
  const int tid = blockIdx.x * 256 + threadIdx.x;  // 0..131071
  const int part = tid & 3, ci = (tid >> 2) & 15, w2 = (tid >> 6) & 15;
  const int h = (tid >> 10) & 15, b = tid >> 14;
  float4 v[9];
  float m = -3.0e38f;
#pragma unroll
  for (int s = 0; s < 9; ++s) {
    const int ki = (s >= 6) ? 2 : (s >= 3) ? 1 : 0, kj = s - 3 * ki;
    const int pi = h - ki, pj = w2 - kj;
    if ((unsigned)pi < (unsigned)P_ && (unsigned)pj < (unsigned)P_) {
      v[s] = *(const float4*)(z + (size_t)(b * P2_ + pi * P_ + pj) * NV_ + s * 256 +
                              ci * 16 + part * 4);
    } else {
      v[s] = make_float4(-3.0e38f, -3.0e38f, -3.0e38f, -3.0e38f);
    }
    m = fmaxf(m, fmaxf(fmaxf(v[s].x, v[s].y), fmaxf(v[s].z, v[s].w)));
  }
  m = fmaxf(m, __shfl_xor(m, 1));
  m = fmaxf(m, __shfl_xor(m, 2));
  float s_ = 0.f;
#pragma unroll
  for (int s = 0; s < 9; ++s) {
    s_ += __expf(v[s].x - m) + __expf(v[s].y - m) + __expf(v[s].z - m) + __expf(v[s].w - m);
  }
  s_ += __shfl_xor(s_, 1);
  s_ += __shfl_xor(s_, 2);
  if (part == 0) {
    gmax[tid >> 2] = m;
    gden[tid >> 2] = s_;
  }
}
}  // namespace

extern "C" void kernel_launch(void* const* d_in, const int* in_sizes, int n_in,
                              void* d_out, int out_size, void* d_ws, size_t ws_size,
                              hipStream_t stream) {
  const float* pose = (const float*)d_in[0];
  const float* act = (const float*)d_in[1];
  const float* w = (const float*)d_in[2];
  const float* ba = (const float*)d_in[3];
  const float* bv = (const float*)d_in[4];
  float* out = (float*)d_out;

  float* z = (float*)d_ws;                  // 3,612,672 floats, layout [pid][k][o]
  float* gm = z + (size_t)B_ * P2_ * NV_;   // 32,768
  float* gd = gm + B_ * H_ * H_ * CI_;      // 32,768
  float* wt = gd + B_ * H_ * H_ * CI_;      // 36,864

  const int NB = B_ * P2_;  // 1568 blocks, one per patch
  transpose_w<<<144, 256, 0, stream>>>(w, wt);
  caps_main<0><<<NB, 512, 0, stream>>>(pose, act, wt, ba, bv, z, gm, gd, z, out);
  seg_reduce<<<512, 256, 0, stream>>>(z, gm, gd);
  caps_main<1><<<NB, 512, 0, stream>>>(pose, act, wt, ba, bv, z, gm, gd, z, out);
  seg_reduce<<<512, 256, 0, stream>>>(z, gm, gd);
  caps_main<2><<<NB, 512, 0, stream>>>(pose, act, wt, ba, bv, z, gm, gd, z, out);
}